// Round 16
// baseline (482.643 us; speedup 1.0000x reference)
//
#include <hip/hip_runtime.h>
#include <math.h>

#define NWALK 32000
#define NNODE 8000
#define NEDGE 64000

typedef __attribute__((ext_vector_type(8))) short short8v;   // 8 bf16 (4 VGPRs)
typedef __attribute__((ext_vector_type(4))) float f32x4;     // MFMA C/D

// workspace layout (float offsets)
static const size_t OFF_WP   = 0;                          // proj A-frags hi/lo: 49152 ushort (24576 f)
static const size_t OFF_ME   = OFF_WP + 5*12288;           // M_edge[192][16]
static const size_t OFF_WMHT = OFF_ME + 3072;              // WmhT[64][192]
static const size_t OFF_WDEG = OFF_WMHT + 12288;           // wdeg[192]
static const size_t OFF_DMAX = OFF_WDEG + 192;             // int degmax (+pad)
static const size_t OFF_E2   = OFF_DMAX + 64;              // E2[64000][192]
static const size_t OFF_H2   = OFF_E2 + (size_t)NEDGE*192; // H2[8000][192]
static const size_t OFF_XGE  = OFF_H2 + (size_t)NNODE*192; // XGE[256000][192]
static const size_t OFF_HW   = OFF_XGE + (size_t)NWALK*8*192; // HW[32000][64]
static const size_t OFF_MND  = OFF_HW + (size_t)NWALK*64;  // M_node[256000] (int)
static const size_t OFF_MDD  = OFF_MND + (size_t)NWALK*8;  // M_dd[256000]
static const size_t OFF_TFP  = OFF_MDD + (size_t)NWALK*8;  // Tf'[8][196] (bih all; bhh folded r,z only)
static const size_t OFF_TBP  = OFF_TFP + 1568;             // Tb'[8][196]
static const size_t OFF_WB   = OFF_TBP + 1568;             // bf16 HI-only A-frags: 3 mats x 12288 ushort

__device__ __forceinline__ float sigm(float x){ return 1.f/(1.f+__expf(-x)); }
__device__ __forceinline__ float tanh_(float x){ float e=__expf(2.f*x); return 1.f-2.f/(e+1.f); }
__device__ __forceinline__ unsigned short f2bf(float x){
  unsigned u = __float_as_uint(x);
  unsigned r = (u + 0x7FFFu + ((u>>16)&1u)) >> 16;   // RNE
  return (unsigned short)r;
}
__device__ __forceinline__ float bf2f(unsigned short h){
  return __uint_as_float(((unsigned)h)<<16);
}

__global__ void k_init(int* dmax){ if (threadIdx.x==0) *dmax = 0; }

// proj A-frags hi/lo for W' = wih_m[:,64:192] (A|B contiguous), 192x128.
// frag f=a*8+c*2+p (a=row-tile 0..11, c=k-chunk 0..3, p=0 hi/1 lo)
__global__ void k_prep_wp(const float* __restrict__ wih_m, unsigned short* __restrict__ WP){
  int idx = blockIdx.x*256 + threadIdx.x;
  if (idx >= 49152) return;
  int f = idx/512, r3 = idx%512;
  int lane = r3>>3, i = r3&7;
  int a = f>>3, c = (f>>1)&3, p = f&1;
  int row = 16*a + (lane&15);
  int k = 32*c + 8*(lane>>4) + i;
  float val = wih_m[row*193 + 64 + k];
  unsigned short hi = f2bf(val);
  WP[idx] = (p==0) ? hi : f2bf(val - bf2f(hi));
}

// bf16 HI-only MFMA A-fragments for whh_wf / whh_wb / whh_m (single-wave tiling).
// frag f = t*2+c (t=row-tile 0..11, c=k-chunk 0..1)
// ushort addr = mat*12288 + f*512 + lane*8 + i
// A[row=16t+(lane&15)][k=32c+8*(lane>>4)+i]
__global__ void k_prep_wb(const float* __restrict__ whh_wf, const float* __restrict__ whh_wb,
                          const float* __restrict__ whh_m, unsigned short* __restrict__ WB){
  int idx = blockIdx.x*256+threadIdx.x;
  if (idx >= 3*12288) return;
  int mat = idx/12288; int r2 = idx%12288;
  int f   = r2/512;    int r3 = r2%512;
  int lane= r3>>3, i = r3&7;
  int t = f>>1, c = f&1;
  int row = 16*t + (lane&15);
  int k = 32*c + 8*(lane>>4) + i;
  const float* W = (mat==0)? whh_wf : ((mat==1)? whh_wb : whh_m);
  WB[idx] = f2bf(W[row*64+k]);
}

// padded gate tables (stride 196): bih always; bhh folded ONLY for r,z rows (g<128).
__global__ void k_prep_tblp(const float* __restrict__ wih_wf,const float* __restrict__ bih_wf,
                            const float* __restrict__ bhh_wf,
                            const float* __restrict__ wih_wb,const float* __restrict__ bih_wb,
                            const float* __restrict__ bhh_wb,
                            float* __restrict__ Tfp, float* __restrict__ Tbp){
  int idx = blockIdx.x*256+threadIdx.x;
  if (idx >= 2*1568) return;
  int which = idx/1568, r = idx%1568;
  int u = r/196, g = r%196;
  float val = 0.f;
  if (g < 192){
    float ang = (float)u * 0.78539816339744831f;
    float s = sinf(ang), cc = cosf(ang);
    if (!which) val = bih_wf[g] + wih_wf[g*2]*s + wih_wf[g*2+1]*cc + (g<128? bhh_wf[g] : 0.f);
    else        val = bih_wb[g] + wih_wb[g*2]*s + wih_wb[g*2+1]*cc + (g<128? bhh_wb[g] : 0.f);
  }
  (which? Tbp : Tfp)[u*196+g] = val;
}

__global__ void k_prep_misc(const float* __restrict__ wih_m, const float* __restrict__ w_edge,
                            float* __restrict__ M, float* __restrict__ WmhT,
                            float* __restrict__ wdeg){
  int idx = blockIdx.x*256+threadIdx.x;
  if (idx < 3072){
    int g = idx >> 4, f = idx & 15;
    float acc = 0.f;
    for (int d=0; d<193; ++d) acc += wih_m[g*193+d]*w_edge[d*16+f];
    M[g*16+f] = acc;
  }
  int j = idx - 3072;
  if (j >= 0 && j < 12288){
    int k = j / 192, g = j % 192;
    WmhT[k*192+g] = wih_m[g*193+k];
  }
  int q = idx - 3072 - 12288;
  if (q >= 0 && q < 192) wdeg[q] = wih_m[q*193+192];
}

// degmax reduce + zero HW (atomicAdd accumulation target)
__global__ void k_degmax(const int* __restrict__ walks, const int* __restrict__ degs,
                         int* __restrict__ dmax, float* __restrict__ HW){
  int idx = blockIdx.x*256+threadIdx.x;
  int v = 0;
  if (idx < NWALK*8) v = degs[walks[idx]];
  #pragma unroll
  for (int off=32; off; off>>=1) v = max(v, __shfl_xor(v, off));
  if ((threadIdx.x & 63)==0) atomicMax(dmax, v);
  for (size_t i=idx; i<(size_t)NWALK*64; i+=256000) HW[i]=0.f;
}

// fused: E2 rows (bih_m always; bhh_m folded only g<128) and H2 rows
__global__ void k_e2h2(const float* __restrict__ e, const float* __restrict__ M,
                       const float* __restrict__ bih_m, const float* __restrict__ bhh_m,
                       const float* __restrict__ h, const float* __restrict__ WmhT,
                       float* __restrict__ E2, float* __restrict__ H2){
  const int bx = blockIdx.x;
  const int g = threadIdx.x;
  if (bx < NEDGE){
    __shared__ float ev[16];
    if (g < 16) ev[g] = e[bx*16+g];
    __syncthreads();
    float acc = bih_m[g] + (g<128? bhh_m[g] : 0.f);
    #pragma unroll
    for (int f=0; f<16; ++f) acc += ev[f]*M[g*16+f];
    E2[(size_t)bx*192+g] = acc;
  } else {
    const int node = bx - NEDGE;
    __shared__ float hv[64];
    if (g < 64) hv[g] = h[node*64+g];
    __syncthreads();
    float acc = 0.f;
    for (int k=0;k<64;++k) acc += hv[k]*WmhT[k*192+g];
    H2[(size_t)node*192+g] = acc;
  }
}

// pack 4 floats -> hi uint2 + lo uint2 (bf16 split)
__device__ __forceinline__ void pack_hilo(const float* hn, uint2* whi, uint2* wlo){
  unsigned short h0=f2bf(hn[0]), h1=f2bf(hn[1]), h2=f2bf(hn[2]), h3=f2bf(hn[3]);
  whi->x = (unsigned)h0 | ((unsigned)h1<<16);
  whi->y = (unsigned)h2 | ((unsigned)h3<<16);
  unsigned short l0=f2bf(hn[0]-bf2f(h0)), l1=f2bf(hn[1]-bf2f(h1));
  unsigned short l2=f2bf(hn[2]-bf2f(h2)), l3=f2bf(hn[3]-bf2f(h3));
  wlo->x = (unsigned)l0 | ((unsigned)l1<<16);
  wlo->y = (unsigned)l2 | ((unsigned)l3<<16);
}

// 12-tile matvec: C[t] = Whi[t] * (hhi + hlo), h exact via hi/lo split.
#define MMSTEP() do { \
  _Pragma("unroll") \
  for (int t=0;t<12;++t){ \
    f32x4 acc_={0.f,0.f,0.f,0.f}; \
    acc_=__builtin_amdgcn_mfma_f32_16x16x32_bf16(afr[2*t],  bh0,acc_,0,0,0); \
    acc_=__builtin_amdgcn_mfma_f32_16x16x32_bf16(afr[2*t+1],bh1,acc_,0,0,0); \
    acc_=__builtin_amdgcn_mfma_f32_16x16x32_bf16(afr[2*t],  bl0,acc_,0,0,0); \
    acc_=__builtin_amdgcn_mfma_f32_16x16x32_bf16(afr[2*t+1],bl1,acc_,0,0,0); \
    C[t]=acc_; \
  } \
} while(0)

// ---------------------------------------------------------------------------
// Single-wave MFMA walk-GRU: 16 walks/wave, full 64 hidden. Weights HI-only
// in VGPRs (24 frags); h carried as bf16 hi/lo via INTRA-WAVE LDS roundtrip
// (R10-pattern, verified equivalent via R11 bit-match). NO barriers in loop.
// blocks [0,500): forward; [500,1000): backward. 64 walks/block.
// ---------------------------------------------------------------------------
__global__ __launch_bounds__(256,1) void k_wgru_m(
    const int* __restrict__ walks, const int* __restrict__ degs,
    const int* __restrict__ dmaxp, const unsigned short* __restrict__ WB,
    const float* __restrict__ Tfp, const float* __restrict__ Tbp,
    const float* __restrict__ bhh_f, const float* __restrict__ bhh_b,
    float* __restrict__ XGE, float* __restrict__ HW,
    int* __restrict__ M_node, float* __restrict__ M_dd)
{
  __shared__ float tbl[1568];
  __shared__ int   m_u[64][8];
  __shared__ unsigned short hhi[4][16][64];   // [wave][walk][j]
  __shared__ unsigned short hlo[4][16][64];
  const int bx=blockIdx.x;
  const int dirb = (bx>=500);
  const int tid=threadIdx.x, wave=tid>>6, lane=tid&63;
  const int wl=lane&15, ag=lane>>4;
  const int vbase=(dirb?bx-500:bx)*64;
  const int v = vbase + wave*16 + wl;

  const float* TS = dirb? Tbp : Tfp;
  const float* BH = dirb? bhh_b : bhh_f;
  float bhhn[16];
  #pragma unroll
  for (int jb=0;jb<4;++jb)
    #pragma unroll
    for (int r=0;r<4;++r)
      bhhn[4*jb+r] = BH[128 + 16*jb + 4*ag + r];   // n-gate hidden bias
  for (int i=tid;i<1568;i+=256) tbl[i]=TS[i];
  if (tid<64){
    const int vv=vbase+tid;
    int w[8];
    #pragma unroll
    for (int i=0;i<8;++i) w[i]=walks[vv*8+i];
    int u[8];
    #pragma unroll
    for (int i=0;i<8;++i){
      int ui=i;
      #pragma unroll
      for (int j=7;j>=0;--j) if (j<=i && w[j]==w[i]) ui=j;   // first occurrence
      u[i]=ui;
    }
    #pragma unroll
    for (int t=0;t<8;++t) m_u[tid][t]=u[7-t];
    if (!dirb){
      const float dmx=(float)(*dmaxp);
      #pragma unroll
      for (int t=0;t<8;++t){
        int nd=w[7-t];
        M_node[(size_t)vv*8+t]=nd;
        M_dd[(size_t)vv*8+t]=(float)degs[nd]/dmx;
      }
    }
  }
  short8v afr[24];
  const short8v* WBv = (const short8v*)(WB + (size_t)dirb*12288);
  #pragma unroll
  for (int f=0;f<24;++f) afr[f]=WBv[f*64+lane];
  __syncthreads();                 // tbl/m_u visible (once, outside loop)

  float hold[16];
  #pragma unroll
  for (int i=0;i<16;++i) hold[i]=0.f;
  char* Hb = (char*)&hhi[wave][0][0];
  char* Lb = (char*)&hlo[wave][0][0];
  const int swz = (wl&7)<<4;
  const int ycol = dirb?64:0;
  const int o0 = (wl*128 + 16*ag) ^ swz;        // k-chunk 0 read offset
  const int o1 = (wl*128 + 64 + 16*ag) ^ swz;   // k-chunk 1

  for (int q=0;q<8;++q){
    const int p_ = dirb?7-q:q;
    f32x4 C[12];
    if (q){
      short8v bh0=*(const short8v*)(Hb+o0), bh1=*(const short8v*)(Hb+o1);
      short8v bl0=*(const short8v*)(Lb+o0), bl1=*(const short8v*)(Lb+o1);
      MMSTEP();
    } else {
      #pragma unroll
      for (int t=0;t<12;++t) C[t]=(f32x4){0.f,0.f,0.f,0.f};
    }
    const int u = m_u[wave*16+wl][p_];
    const float* tb = &tbl[u*196];
    float hnew[16];
    #pragma unroll
    for (int jb=0;jb<4;++jb){
      const int j0 = 16*jb + 4*ag;
      f32x4 xr = *(const f32x4*)(tb + j0);
      f32x4 xz = *(const f32x4*)(tb + 64 + j0);
      f32x4 xn = *(const f32x4*)(tb + 128 + j0);
      #pragma unroll
      for (int r=0;r<4;++r){
        float rr = sigm(xr[r] + C[jb][r]);
        float zz = sigm(xz[r] + C[4+jb][r]);
        float nn = tanh_(xn[r] + rr*(C[8+jb][r] + bhhn[4*jb+r]));   // bhh_n inside r*()
        hnew[4*jb+r] = (1.f-zz)*nn + zz*hold[4*jb+r];
      }
    }
    #pragma unroll
    for (int jb=0;jb<4;++jb){
      const int j0 = 16*jb + 4*ag;
      *(f32x4*)&XGE[((size_t)v*8+p_)*192 + ycol + j0] =
        (f32x4){hnew[4*jb],hnew[4*jb+1],hnew[4*jb+2],hnew[4*jb+3]};
      uint2 whi, wlo;
      pack_hilo(&hnew[4*jb], &whi, &wlo);
      const int off = (wl*128 + j0*2) ^ swz;
      *(uint2*)(Hb+off)=whi;
      *(uint2*)(Lb+off)=wlo;
    }
    #pragma unroll
    for (int i=0;i<16;++i) hold[i]=hnew[i];
    asm volatile("" ::: "memory");   // order LDS writes before next-iter reads
  }
  #pragma unroll
  for (int jb=0;jb<4;++jb)
    #pragma unroll
    for (int r=0;r<4;++r)
      atomicAdd(&HW[(size_t)v*64 + 16*jb+4*ag + r], 0.5f*hold[4*jb+r]);
}

// Single-wave MFMA main-GRU: same structure, 15 steps, xg from XGE/E2.
__global__ __launch_bounds__(256,1) void k_main_m(
    const int* __restrict__ eids, const unsigned short* __restrict__ WB,
    const float* __restrict__ bhh_m,
    const float* __restrict__ XGE, const float* __restrict__ E2,
    const float* __restrict__ HW, float* __restrict__ out)
{
  __shared__ unsigned short hhi[4][16][64];
  __shared__ unsigned short hlo[4][16][64];
  const int tid=threadIdx.x, wave=tid>>6, lane=tid&63;
  const int wl=lane&15, ag=lane>>4;
  const int v = blockIdx.x*64 + wave*16 + wl;
  float bhhn[16];
  #pragma unroll
  for (int jb=0;jb<4;++jb)
    #pragma unroll
    for (int r=0;r<4;++r)
      bhhn[4*jb+r] = bhh_m[128 + 16*jb + 4*ag + r];
  short8v afr[24];
  const short8v* WBv = (const short8v*)(WB + (size_t)2*12288);
  #pragma unroll
  for (int f=0;f<24;++f) afr[f]=WBv[f*64+lane];
  char* Hb = (char*)&hhi[wave][0][0];
  char* Lb = (char*)&hlo[wave][0][0];
  const int swz=(wl&7)<<4;
  const int o0 = (wl*128 + 16*ag) ^ swz;
  const int o1 = (wl*128 + 64 + 16*ag) ^ swz;
  float hold[16];
  #pragma unroll
  for (int jb=0;jb<4;++jb){
    const int j0 = 16*jb + 4*ag;
    f32x4 hv = *(const f32x4*)&HW[(size_t)v*64 + j0];
    #pragma unroll
    for (int r=0;r<4;++r) hold[4*jb+r]=hv[r];
    uint2 whi, wlo;
    pack_hilo(&hold[4*jb], &whi, &wlo);
    const int off = (wl*128 + j0*2) ^ swz;
    *(uint2*)(Hb+off)=whi;
    *(uint2*)(Lb+off)=wlo;
  }
  asm volatile("" ::: "memory");
  for (int t=0;t<15;++t){
    short8v bh0=*(const short8v*)(Hb+o0), bh1=*(const short8v*)(Hb+o1);
    short8v bl0=*(const short8v*)(Lb+o0), bl1=*(const short8v*)(Lb+o1);
    f32x4 C[12];
    MMSTEP();
    const float* xg;
    if (t&1) xg = E2 + (size_t)eids[v*7+(t>>1)]*192;
    else     xg = XGE + ((size_t)v*8+(t>>1))*192;
    float hnew[16];
    #pragma unroll
    for (int jb=0;jb<4;++jb){
      const int j0 = 16*jb + 4*ag;
      f32x4 xr = *(const f32x4*)(xg + j0);
      f32x4 xz = *(const f32x4*)(xg + 64 + j0);
      f32x4 xn = *(const f32x4*)(xg + 128 + j0);
      #pragma unroll
      for (int r=0;r<4;++r){
        float rr=sigm(xr[r]+C[jb][r]);
        float zz=sigm(xz[r]+C[4+jb][r]);
        float nn=tanh_(xn[r]+rr*(C[8+jb][r] + bhhn[4*jb+r]));   // bhh_n inside r*()
        hnew[4*jb+r]=(1.f-zz)*nn+zz*hold[4*jb+r];
      }
    }
    #pragma unroll
    for (int jb=0;jb<4;++jb){
      const int j0 = 16*jb + 4*ag;
      uint2 whi, wlo;
      pack_hilo(&hnew[4*jb], &whi, &wlo);
      const int off = (wl*128 + j0*2) ^ swz;
      *(uint2*)(Hb+off)=whi;
      *(uint2*)(Lb+off)=wlo;
    }
    #pragma unroll
    for (int i=0;i<16;++i) hold[i]=hnew[i];
    asm volatile("" ::: "memory");
  }
  #pragma unroll
  for (int jb=0;jb<4;++jb){
    const int j0 = 16*jb + 4*ag;
    *(f32x4*)&out[(size_t)v*64 + j0] =
      (f32x4){hold[4*jb],hold[4*jb+1],hold[4*jb+2],hold[4*jb+3]};
  }
}

// ---------------------------------------------------------------------------
// MFMA projection (unchanged from R15, verified): full 3-term hi/lo.
// ---------------------------------------------------------------------------
__global__ __launch_bounds__(256,1) void k_proj_m(
    const unsigned short* __restrict__ WP,
    const float* __restrict__ H2, const float* __restrict__ wdeg,
    const float* __restrict__ bihm, const float* __restrict__ bhhm,
    const int* __restrict__ M_node, const float* __restrict__ M_dd,
    float* __restrict__ XGE)
{
  __shared__ __align__(16) unsigned short yh[8192];   // 64 rows x 128 bf16 (hi)
  __shared__ __align__(16) unsigned short yl[8192];   // (lo)
  __shared__ __align__(16) float sb_bias[192];
  __shared__ __align__(16) float sb_wdeg[192];
  __shared__ int   nd_l[64];
  __shared__ float dd_l[64];

  const int tid=threadIdx.x, wv=tid>>6, lane=tid&63;
  const int wl=lane&15, ag=lane>>4;
  const size_t r0 = (size_t)blockIdx.x*64;

  if (tid<192){ sb_wdeg[tid]=wdeg[tid]; sb_bias[tid]=bihm[tid] + (tid<128? bhhm[tid] : 0.f); }
  if (tid<64){ nd_l[tid]=M_node[r0+tid]; dd_l[tid]=M_dd[r0+tid]; }
  for (int i=tid;i<2048;i+=256){
    const int row=i>>5, j0=(i&31)*4;
    f32x4 yv = *(const f32x4*)&XGE[(r0+row)*192 + j0];
    float tmp[4] = {yv[0],yv[1],yv[2],yv[3]};
    uint2 whi, wlo;
    pack_hilo(tmp, &whi, &wlo);
    const int off = (j0*2) ^ ((row&7)<<4);
    *(uint2*)((char*)yh + row*256 + off) = whi;
    *(uint2*)((char*)yl + row*256 + off) = wlo;
  }
  __syncthreads();

  const int swz = (wl&7)<<4;
  const char* Hb = (const char*)yh + (16*wv+wl)*256;
  const char* Lb = (const char*)yl + (16*wv+wl)*256;
  short8v bh[4], bl[4];
  #pragma unroll
  for (int c=0;c<4;++c){
    bh[c] = *(const short8v*)(Hb + ((c*64 + 16*ag) ^ swz));
    bl[c] = *(const short8v*)(Lb + ((c*64 + 16*ag) ^ swz));
  }

  const short8v* WPv = (const short8v*)WP;
  const int   nd = nd_l[16*wv+wl];
  const float dd = dd_l[16*wv+wl];
  const size_t orow = (r0 + 16*wv + wl)*192;
  const size_t h2b  = (size_t)nd*192;

  #pragma unroll 2
  for (int a=0;a<12;++a){
    f32x4 C = {0.f,0.f,0.f,0.f};
    #pragma unroll
    for (int c=0;c<4;++c){
      short8v whi_ = WPv[(a*8+c*2+0)*64 + lane];
      short8v wlo_ = WPv[(a*8+c*2+1)*64 + lane];
      C = __builtin_amdgcn_mfma_f32_16x16x32_bf16(whi_, bh[c], C, 0,0,0);
      C = __builtin_amdgcn_mfma_f32_16x16x32_bf16(whi_, bl[c], C, 0,0,0);
      C = __builtin_amdgcn_mfma_f32_16x16x32_bf16(wlo_, bh[c], C, 0,0,0);
    }
    const int g0 = 16*a + 4*ag;
    f32x4 h2v = *(const f32x4*)&H2[h2b + g0];
    f32x4 wdv = *(const f32x4*)&sb_wdeg[g0];
    f32x4 bv  = *(const f32x4*)&sb_bias[g0];
    f32x4 o;
    #pragma unroll
    for (int r=0;r<4;++r) o[r] = C[r] + h2v[r] + dd*wdv[r] + bv[r];
    *(f32x4*)&XGE[orow + g0] = o;
  }
}

extern "C" void kernel_launch(void* const* d_in, const int* in_sizes, int n_in,
                              void* d_out, int out_size, void* d_ws, size_t ws_size,
                              hipStream_t stream)
{
  const float* h      = (const float*)d_in[0];
  const float* e      = (const float*)d_in[2];
  const int*   walks  = (const int*)d_in[3];
  const int*   eids   = (const int*)d_in[4];
  const int*   degs   = (const int*)d_in[5];
  const float* wih_wf = (const float*)d_in[6];
  const float* whh_wf = (const float*)d_in[7];
  const float* bih_wf = (const float*)d_in[8];
  const float* bhh_wf = (const float*)d_in[9];
  const float* wih_wb = (const float*)d_in[10];
  const float* whh_wb = (const float*)d_in[11];
  const float* bih_wb = (const float*)d_in[12];
  const float* bhh_wb = (const float*)d_in[13];
  const float* wih_m  = (const float*)d_in[14];
  const float* whh_m  = (const float*)d_in[15];
  const float* bih_m  = (const float*)d_in[16];
  const float* bhh_m  = (const float*)d_in[17];
  const float* w_edge = (const float*)d_in[18];
  float* out = (float*)d_out;
  float* wsf = (float*)d_ws;

  unsigned short* WP = (unsigned short*)(wsf + OFF_WP);
  float* Me   = wsf + OFF_ME;
  float* WmhT = wsf + OFF_WMHT;
  float* wdeg = wsf + OFF_WDEG;
  int*   dmax = (int*)(wsf + OFF_DMAX);
  float* E2   = wsf + OFF_E2;
  float* H2   = wsf + OFF_H2;
  float* XGE  = wsf + OFF_XGE;
  float* HW   = wsf + OFF_HW;
  int*   MND  = (int*)(wsf + OFF_MND);
  float* MDD  = wsf + OFF_MDD;
  float* Tfp  = wsf + OFF_TFP;
  float* Tbp  = wsf + OFF_TBP;
  unsigned short* WB = (unsigned short*)(wsf + OFF_WB);

  hipLaunchKernelGGL(k_init,      dim3(1),    dim3(64), 0, stream, dmax);
  hipLaunchKernelGGL(k_prep_wp,   dim3(192),  dim3(256),0, stream, wih_m, WP);
  hipLaunchKernelGGL(k_prep_wb,   dim3(144),  dim3(256),0, stream, whh_wf,whh_wb,whh_m, WB);
  hipLaunchKernelGGL(k_prep_tblp, dim3(13),   dim3(256),0, stream,
                     wih_wf,bih_wf,bhh_wf, wih_wb,bih_wb,bhh_wb, Tfp,Tbp);
  hipLaunchKernelGGL(k_prep_misc, dim3(61),   dim3(256),0, stream, wih_m,w_edge,Me,WmhT,wdeg);
  hipLaunchKernelGGL(k_degmax,    dim3(1000), dim3(256),0, stream, walks,degs,dmax,HW);
  hipLaunchKernelGGL(k_e2h2,      dim3(NEDGE+NNODE),dim3(192),0, stream,
                     e,Me,bih_m,bhh_m,h,WmhT,E2,H2);
  hipLaunchKernelGGL(k_wgru_m,    dim3(1000), dim3(256),0, stream,
                     walks,degs,dmax, WB, Tfp,Tbp, bhh_wf,bhh_wb, XGE,HW,MND,MDD);
  hipLaunchKernelGGL(k_proj_m,    dim3(4000), dim3(256),0, stream,
                     WP, H2, wdeg, bih_m, bhh_m, MND, MDD, XGE);
  hipLaunchKernelGGL(k_main_m,    dim3(500),  dim3(256),0, stream,
                     eids, WB, bhh_m, XGE, E2, HW, out);
  (void)in_sizes;(void)n_in;(void)out_size;(void)ws_size;
}

// Round 17
// 448.133 us; speedup vs baseline: 1.0770x; 1.0770x over previous
//
#include <hip/hip_runtime.h>
#include <math.h>

#define NWALK 32000
#define NNODE 8000
#define NEDGE 64000

typedef __attribute__((ext_vector_type(8))) short short8v;   // 8 bf16 (4 VGPRs)
typedef __attribute__((ext_vector_type(4))) float f32x4;     // MFMA C/D

// workspace layout (float offsets)
static const size_t OFF_WP   = 0;                          // proj A-frags hi/lo: 49152 ushort (24576 f)
static const size_t OFF_ME   = OFF_WP + 5*12288;           // M_edge[192][16]
static const size_t OFF_WMHT = OFF_ME + 3072;              // WmhT[64][192]
static const size_t OFF_WDEG = OFF_WMHT + 12288;           // wdeg[192]
static const size_t OFF_DMAX = OFF_WDEG + 192;             // int degmax (+pad)
static const size_t OFF_E2   = OFF_DMAX + 64;              // E2[64000][192]
static const size_t OFF_H2   = OFF_E2 + (size_t)NEDGE*192; // H2[8000][192]
static const size_t OFF_XGE  = OFF_H2 + (size_t)NNODE*192; // XGE[256000][192]
static const size_t OFF_HW   = OFF_XGE + (size_t)NWALK*8*192; // HW[32000][64]
static const size_t OFF_MND  = OFF_HW + (size_t)NWALK*64;  // M_node[256000] (int)
static const size_t OFF_MDD  = OFF_MND + (size_t)NWALK*8;  // M_dd[256000]
static const size_t OFF_TFP  = OFF_MDD + (size_t)NWALK*8;  // Tf'[8][196] (bih all; bhh folded r,z only)
static const size_t OFF_TBP  = OFF_TFP + 1568;             // Tb'[8][196]
static const size_t OFF_WB   = OFF_TBP + 1568;             // bf16 hi/lo A-frags: 3 mats x 2 hh x 12288 ushort

__device__ __forceinline__ float sigm(float x){ return 1.f/(1.f+__expf(-x)); }
__device__ __forceinline__ float tanh_(float x){ float e=__expf(2.f*x); return 1.f-2.f/(e+1.f); }
__device__ __forceinline__ unsigned short f2bf(float x){
  unsigned u = __float_as_uint(x);
  unsigned r = (u + 0x7FFFu + ((u>>16)&1u)) >> 16;   // RNE
  return (unsigned short)r;
}
__device__ __forceinline__ float bf2f(unsigned short h){
  return __uint_as_float(((unsigned)h)<<16);
}

__global__ void k_init(int* dmax){ if (threadIdx.x==0) *dmax = 0; }

// proj A-frags hi/lo for W' = wih_m[:,64:192] (A|B contiguous), 192x128.
// frag f=a*8+c*2+p (a=row-tile 0..11, c=k-chunk 0..3, p=0 hi/1 lo)
__global__ void k_prep_wp(const float* __restrict__ wih_m, unsigned short* __restrict__ WP){
  int idx = blockIdx.x*256 + threadIdx.x;
  if (idx >= 49152) return;
  int f = idx/512, r3 = idx%512;
  int lane = r3>>3, i = r3&7;
  int a = f>>3, c = (f>>1)&3, p = f&1;
  int row = 16*a + (lane&15);
  int k = 32*c + 8*(lane>>4) + i;
  float val = wih_m[row*193 + 64 + k];
  unsigned short hi = f2bf(val);
  WP[idx] = (p==0) ? hi : f2bf(val - bf2f(hi));
}

// bf16 hi/lo MFMA A-fragments for whh_wf / whh_wb / whh_m, split by hidden-half hh.
__global__ void k_prep_wb(const float* __restrict__ whh_wf, const float* __restrict__ whh_wb,
                          const float* __restrict__ whh_m, unsigned short* __restrict__ WB){
  int idx = blockIdx.x*256+threadIdx.x;
  if (idx >= 3*2*12288) return;
  int mat = idx/24576; int r1 = idx%24576;
  int hh  = r1/12288;  int r2 = r1%12288;
  int f   = r2/512;    int r3 = r2%512;
  int lane= r3>>3, i = r3&7;
  int a = f>>2, c=(f>>1)&1, p=f&1;
  int t = 4*(a>>1) + 2*hh + (a&1);
  int row = 16*t + (lane&15);
  int k = 32*c + 8*(lane>>4) + i;
  const float* W = (mat==0)? whh_wf : ((mat==1)? whh_wb : whh_m);
  float val = W[row*64+k];
  unsigned short hi = f2bf(val);
  WB[idx] = (p==0) ? hi : f2bf(val - bf2f(hi));
}

// padded gate tables (stride 196): bih always; bhh folded ONLY for r,z rows (g<128).
__global__ void k_prep_tblp(const float* __restrict__ wih_wf,const float* __restrict__ bih_wf,
                            const float* __restrict__ bhh_wf,
                            const float* __restrict__ wih_wb,const float* __restrict__ bih_wb,
                            const float* __restrict__ bhh_wb,
                            float* __restrict__ Tfp, float* __restrict__ Tbp){
  int idx = blockIdx.x*256+threadIdx.x;
  if (idx >= 2*1568) return;
  int which = idx/1568, r = idx%1568;
  int u = r/196, g = r%196;
  float val = 0.f;
  if (g < 192){
    float ang = (float)u * 0.78539816339744831f;
    float s = sinf(ang), cc = cosf(ang);
    if (!which) val = bih_wf[g] + wih_wf[g*2]*s + wih_wf[g*2+1]*cc + (g<128? bhh_wf[g] : 0.f);
    else        val = bih_wb[g] + wih_wb[g*2]*s + wih_wb[g*2+1]*cc + (g<128? bhh_wb[g] : 0.f);
  }
  (which? Tbp : Tfp)[u*196+g] = val;
}

__global__ void k_prep_misc(const float* __restrict__ wih_m, const float* __restrict__ w_edge,
                            float* __restrict__ M, float* __restrict__ WmhT,
                            float* __restrict__ wdeg){
  int idx = blockIdx.x*256+threadIdx.x;
  if (idx < 3072){
    int g = idx >> 4, f = idx & 15;
    float acc = 0.f;
    for (int d=0; d<193; ++d) acc += wih_m[g*193+d]*w_edge[d*16+f];
    M[g*16+f] = acc;
  }
  int j = idx - 3072;
  if (j >= 0 && j < 12288){
    int k = j / 192, g = j % 192;
    WmhT[k*192+g] = wih_m[g*193+k];
  }
  int q = idx - 3072 - 12288;
  if (q >= 0 && q < 192) wdeg[q] = wih_m[q*193+192];
}

// degmax reduce + zero HW (atomicAdd accumulation target)
__global__ void k_degmax(const int* __restrict__ walks, const int* __restrict__ degs,
                         int* __restrict__ dmax, float* __restrict__ HW){
  int idx = blockIdx.x*256+threadIdx.x;
  int v = 0;
  if (idx < NWALK*8) v = degs[walks[idx]];
  #pragma unroll
  for (int off=32; off; off>>=1) v = max(v, __shfl_xor(v, off));
  if ((threadIdx.x & 63)==0) atomicMax(dmax, v);
  for (size_t i=idx; i<(size_t)NWALK*64; i+=256000) HW[i]=0.f;
}

// fused: E2 rows (bih_m always; bhh_m folded only g<128) and H2 rows
__global__ void k_e2h2(const float* __restrict__ e, const float* __restrict__ M,
                       const float* __restrict__ bih_m, const float* __restrict__ bhh_m,
                       const float* __restrict__ h, const float* __restrict__ WmhT,
                       float* __restrict__ E2, float* __restrict__ H2){
  const int bx = blockIdx.x;
  const int g = threadIdx.x;
  if (bx < NEDGE){
    __shared__ float ev[16];
    if (g < 16) ev[g] = e[bx*16+g];
    __syncthreads();
    float acc = bih_m[g] + (g<128? bhh_m[g] : 0.f);
    #pragma unroll
    for (int f=0; f<16; ++f) acc += ev[f]*M[g*16+f];
    E2[(size_t)bx*192+g] = acc;
  } else {
    const int node = bx - NEDGE;
    __shared__ float hv[64];
    if (g < 64) hv[g] = h[node*64+g];
    __syncthreads();
    float acc = 0.f;
    for (int k=0;k<64;++k) acc += hv[k]*WmhT[k*192+g];
    H2[(size_t)node*192+g] = acc;
  }
}

// 6 MFMA hi/lo-split matvec chunk for one 16-row tile a:
#define MM6(a, BH0, BH1, BL0, BL1, OUT) do { \
  f32x4 acc_={0.f,0.f,0.f,0.f}; \
  acc_=__builtin_amdgcn_mfma_f32_16x16x32_bf16(afr[(a)*4+0],BH0,acc_,0,0,0); \
  acc_=__builtin_amdgcn_mfma_f32_16x16x32_bf16(afr[(a)*4+2],BH1,acc_,0,0,0); \
  acc_=__builtin_amdgcn_mfma_f32_16x16x32_bf16(afr[(a)*4+0],BL0,acc_,0,0,0); \
  acc_=__builtin_amdgcn_mfma_f32_16x16x32_bf16(afr[(a)*4+2],BL1,acc_,0,0,0); \
  acc_=__builtin_amdgcn_mfma_f32_16x16x32_bf16(afr[(a)*4+1],BH0,acc_,0,0,0); \
  acc_=__builtin_amdgcn_mfma_f32_16x16x32_bf16(afr[(a)*4+3],BH1,acc_,0,0,0); \
  OUT=acc_; \
} while(0)

// pack 4 floats -> hi uint2 + lo uint2 (bf16 split)
__device__ __forceinline__ void pack_hilo(const float* hn, uint2* whi, uint2* wlo){
  unsigned short h0=f2bf(hn[0]), h1=f2bf(hn[1]), h2=f2bf(hn[2]), h3=f2bf(hn[3]);
  whi->x = (unsigned)h0 | ((unsigned)h1<<16);
  whi->y = (unsigned)h2 | ((unsigned)h3<<16);
  unsigned short l0=f2bf(hn[0]-bf2f(h0)), l1=f2bf(hn[1]-bf2f(h1));
  unsigned short l2=f2bf(hn[2]-bf2f(h2)), l3=f2bf(hn[3]-bf2f(h3));
  wlo->x = (unsigned)l0 | ((unsigned)l1<<16);
  wlo->y = (unsigned)l2 | ((unsigned)l3<<16);
}

// ---------------------------------------------------------------------------
// MFMA walk-GRU, hi/lo split. 256 thr = 2 groups x 2 waves; 16 walks/group.
// Wave hh handles hidden j in [32hh, 32hh+32). n-gate bhh kept in regs,
// applied INSIDE r*( ). blocks [0,1000): forward; [1000,2000): backward.
// ---------------------------------------------------------------------------
__global__ __launch_bounds__(256,1) void k_wgru_m(
    const int* __restrict__ walks, const int* __restrict__ degs,
    const int* __restrict__ dmaxp, const unsigned short* __restrict__ WB,
    const float* __restrict__ Tfp, const float* __restrict__ Tbp,
    const float* __restrict__ bhh_f, const float* __restrict__ bhh_b,
    float* __restrict__ XGE, float* __restrict__ HW,
    int* __restrict__ M_node, float* __restrict__ M_dd)
{
  __shared__ float tbl[1568];
  __shared__ int   m_u[32][8];
  __shared__ unsigned short hhi[2][2][16][64];   // [buf][grp][walk][j]
  __shared__ unsigned short hlo[2][2][16][64];
  const int bx=blockIdx.x;
  const int dirb = (bx>=1000);
  const int tid=threadIdx.x, wave=tid>>6, lane=tid&63;
  const int grp=wave>>1, hh=wave&1;
  const int wl=lane&15, ag=lane>>4;
  const int vbase=(dirb?bx-1000:bx)*32;
  const int v = vbase + grp*16 + wl;

  const float* TS = dirb? Tbp : Tfp;
  const float* BH = dirb? bhh_b : bhh_f;
  float bhhn[8];
  #pragma unroll
  for (int b=0;b<2;++b)
    #pragma unroll
    for (int r=0;r<4;++r)
      bhhn[4*b+r] = BH[128 + 32*hh + 16*b + 4*ag + r];   // n-gate hidden bias
  for (int i=tid;i<1568;i+=256) tbl[i]=TS[i];
  if (tid<32){
    const int vv=vbase+tid;
    int w[8];
    #pragma unroll
    for (int i=0;i<8;++i) w[i]=walks[vv*8+i];
    int u[8];
    #pragma unroll
    for (int i=0;i<8;++i){
      int ui=i;
      #pragma unroll
      for (int j=7;j>=0;--j) if (j<=i && w[j]==w[i]) ui=j;   // first occurrence
      u[i]=ui;
    }
    #pragma unroll
    for (int t=0;t<8;++t) m_u[tid][t]=u[7-t];
    if (!dirb){
      const float dmx=(float)(*dmaxp);
      #pragma unroll
      for (int t=0;t<8;++t){
        int nd=w[7-t];
        M_node[(size_t)vv*8+t]=nd;
        M_dd[(size_t)vv*8+t]=(float)degs[nd]/dmx;
      }
    }
  }
  short8v afr[24];
  const short8v* WBv = (const short8v*)(WB + (size_t)(dirb*2+hh)*12288);
  #pragma unroll
  for (int f=0;f<24;++f) afr[f]=WBv[f*64+lane];
  __syncthreads();

  float hold[8];
  #pragma unroll
  for (int i=0;i<8;++i) hold[i]=0.f;
  const int swz = (wl&7)<<4;
  const int ycol = dirb?64:0;
  const int o0 = (wl*128 + 16*ag) ^ swz;        // k-chunk 0 read offset
  const int o1 = (wl*128 + 64 + 16*ag) ^ swz;   // k-chunk 1

  for (int q=0;q<8;++q){
    const int p_ = dirb?7-q:q;
    const int cur = q&1;
    f32x4 C[6];
    if (q){
      const char* Hb=(const char*)&hhi[cur][grp][0][0];
      const char* Lb=(const char*)&hlo[cur][grp][0][0];
      short8v bh0=*(const short8v*)(Hb+o0), bh1=*(const short8v*)(Hb+o1);
      short8v bl0=*(const short8v*)(Lb+o0), bl1=*(const short8v*)(Lb+o1);
      MM6(0,bh0,bh1,bl0,bl1,C[0]); MM6(1,bh0,bh1,bl0,bl1,C[1]);
      MM6(2,bh0,bh1,bl0,bl1,C[2]); MM6(3,bh0,bh1,bl0,bl1,C[3]);
      MM6(4,bh0,bh1,bl0,bl1,C[4]); MM6(5,bh0,bh1,bl0,bl1,C[5]);
    } else {
      #pragma unroll
      for (int a=0;a<6;++a) C[a]=(f32x4){0.f,0.f,0.f,0.f};
    }
    const int u = m_u[grp*16+wl][p_];
    const float* tb = &tbl[u*196];
    float hnew[8];
    #pragma unroll
    for (int b=0;b<2;++b){
      const int j0 = 32*hh + 16*b + 4*ag;
      f32x4 xr = *(const f32x4*)(tb + j0);
      f32x4 xz = *(const f32x4*)(tb + 64 + j0);
      f32x4 xn = *(const f32x4*)(tb + 128 + j0);
      #pragma unroll
      for (int r=0;r<4;++r){
        float rr = sigm(xr[r] + C[b][r]);
        float zz = sigm(xz[r] + C[2+b][r]);
        float nn = tanh_(xn[r] + rr*(C[4+b][r] + bhhn[4*b+r]));   // bhh_n inside r*()
        hnew[4*b+r] = (1.f-zz)*nn + zz*hold[4*b+r];
      }
    }
    char* Hw=(char*)&hhi[cur^1][grp][0][0];
    char* Lw=(char*)&hlo[cur^1][grp][0][0];
    #pragma unroll
    for (int b=0;b<2;++b){
      const int j0 = 32*hh + 16*b + 4*ag;
      *(f32x4*)&XGE[((size_t)v*8+p_)*192 + ycol + j0] =
        (f32x4){hnew[4*b],hnew[4*b+1],hnew[4*b+2],hnew[4*b+3]};
      uint2 whi, wlo;
      pack_hilo(&hnew[4*b], &whi, &wlo);
      const int off = (wl*128 + j0*2) ^ swz;
      *(uint2*)(Hw+off)=whi;
      *(uint2*)(Lw+off)=wlo;
    }
    #pragma unroll
    for (int i=0;i<8;++i) hold[i]=hnew[i];
    __syncthreads();
  }
  #pragma unroll
  for (int b=0;b<2;++b)
    #pragma unroll
    for (int r=0;r<4;++r)
      atomicAdd(&HW[(size_t)v*64 + 32*hh+16*b+4*ag + r], 0.5f*hold[4*b+r]);
}

// MFMA main-GRU, hi/lo split, same 2-wave split; 15 steps; xg from XGE/E2.
__global__ __launch_bounds__(256,1) void k_main_m(
    const int* __restrict__ eids, const unsigned short* __restrict__ WB,
    const float* __restrict__ bhh_m,
    const float* __restrict__ XGE, const float* __restrict__ E2,
    const float* __restrict__ HW, float* __restrict__ out)
{
  __shared__ unsigned short hhi[2][2][16][64];
  __shared__ unsigned short hlo[2][2][16][64];
  const int tid=threadIdx.x, wave=tid>>6, lane=tid&63;
  const int grp=wave>>1, hh=wave&1;
  const int wl=lane&15, ag=lane>>4;
  const int v = blockIdx.x*32 + grp*16 + wl;
  float bhhn[8];
  #pragma unroll
  for (int b=0;b<2;++b)
    #pragma unroll
    for (int r=0;r<4;++r)
      bhhn[4*b+r] = bhh_m[128 + 32*hh + 16*b + 4*ag + r];
  short8v afr[24];
  const short8v* WBv = (const short8v*)(WB + (size_t)(2*2+hh)*12288);
  #pragma unroll
  for (int f=0;f<24;++f) afr[f]=WBv[f*64+lane];
  const int swz=(wl&7)<<4;
  const int o0 = (wl*128 + 16*ag) ^ swz;
  const int o1 = (wl*128 + 64 + 16*ag) ^ swz;
  float hold[8];
  {
    char* Hw=(char*)&hhi[0][grp][0][0];
    char* Lw=(char*)&hlo[0][grp][0][0];
    #pragma unroll
    for (int b=0;b<2;++b){
      const int j0 = 32*hh + 16*b + 4*ag;
      f32x4 hv = *(const f32x4*)&HW[(size_t)v*64 + j0];
      #pragma unroll
      for (int r=0;r<4;++r) hold[4*b+r]=hv[r];
      uint2 whi, wlo;
      pack_hilo(&hold[4*b], &whi, &wlo);
      const int off = (wl*128 + j0*2) ^ swz;
      *(uint2*)(Hw+off)=whi;
      *(uint2*)(Lw+off)=wlo;
    }
  }
  __syncthreads();
  for (int t=0;t<15;++t){
    const int cur = t&1;
    const char* Hb=(const char*)&hhi[cur][grp][0][0];
    const char* Lb=(const char*)&hlo[cur][grp][0][0];
    short8v bh0=*(const short8v*)(Hb+o0), bh1=*(const short8v*)(Hb+o1);
    short8v bl0=*(const short8v*)(Lb+o0), bl1=*(const short8v*)(Lb+o1);
    f32x4 C[6];
    MM6(0,bh0,bh1,bl0,bl1,C[0]); MM6(1,bh0,bh1,bl0,bl1,C[1]);
    MM6(2,bh0,bh1,bl0,bl1,C[2]); MM6(3,bh0,bh1,bl0,bl1,C[3]);
    MM6(4,bh0,bh1,bl0,bl1,C[4]); MM6(5,bh0,bh1,bl0,bl1,C[5]);
    const float* xg;
    if (t&1) xg = E2 + (size_t)eids[v*7+(t>>1)]*192;
    else     xg = XGE + ((size_t)v*8+(t>>1))*192;
    float hnew[8];
    #pragma unroll
    for (int b=0;b<2;++b){
      const int j0 = 32*hh + 16*b + 4*ag;
      f32x4 xr = *(const f32x4*)(xg + j0);
      f32x4 xz = *(const f32x4*)(xg + 64 + j0);
      f32x4 xn = *(const f32x4*)(xg + 128 + j0);
      #pragma unroll
      for (int r=0;r<4;++r){
        float rr=sigm(xr[r]+C[b][r]);
        float zz=sigm(xz[r]+C[2+b][r]);
        float nn=tanh_(xn[r]+rr*(C[4+b][r] + bhhn[4*b+r]));   // bhh_n inside r*()
        hnew[4*b+r]=(1.f-zz)*nn+zz*hold[4*b+r];
      }
    }
    char* Hw=(char*)&hhi[cur^1][grp][0][0];
    char* Lw=(char*)&hlo[cur^1][grp][0][0];
    #pragma unroll
    for (int b=0;b<2;++b){
      const int j0 = 32*hh + 16*b + 4*ag;
      uint2 whi, wlo;
      pack_hilo(&hnew[4*b], &whi, &wlo);
      const int off = (wl*128 + j0*2) ^ swz;
      *(uint2*)(Hw+off)=whi;
      *(uint2*)(Lw+off)=wlo;
    }
    #pragma unroll
    for (int i=0;i<8;++i) hold[i]=hnew[i];
    __syncthreads();
  }
  #pragma unroll
  for (int b=0;b<2;++b){
    const int j0 = 32*hh + 16*b + 4*ag;
    *(f32x4*)&out[(size_t)v*64 + j0] =
      (f32x4){hold[4*b],hold[4*b+1],hold[4*b+2],hold[4*b+3]};
  }
}

// ---------------------------------------------------------------------------
// MFMA projection: XGE row <- W'^T [yf;yb] + H2[node] + dd*wdeg + bias.
// ---------------------------------------------------------------------------
__global__ __launch_bounds__(256,1) void k_proj_m(
    const unsigned short* __restrict__ WP,
    const float* __restrict__ H2, const float* __restrict__ wdeg,
    const float* __restrict__ bihm, const float* __restrict__ bhhm,
    const int* __restrict__ M_node, const float* __restrict__ M_dd,
    float* __restrict__ XGE)
{
  __shared__ __align__(16) unsigned short yh[8192];   // 64 rows x 128 bf16 (hi)
  __shared__ __align__(16) unsigned short yl[8192];   // (lo)
  __shared__ __align__(16) float sb_bias[192];
  __shared__ __align__(16) float sb_wdeg[192];
  __shared__ int   nd_l[64];
  __shared__ float dd_l[64];

  const int tid=threadIdx.x, wv=tid>>6, lane=tid&63;
  const int wl=lane&15, ag=lane>>4;
  const size_t r0 = (size_t)blockIdx.x*64;

  if (tid<192){ sb_wdeg[tid]=wdeg[tid]; sb_bias[tid]=bihm[tid] + (tid<128? bhhm[tid] : 0.f); }
  if (tid<64){ nd_l[tid]=M_node[r0+tid]; dd_l[tid]=M_dd[r0+tid]; }
  // stage y (cols 0:128) as bf16 hi/lo, XOR-swizzled rows
  for (int i=tid;i<2048;i+=256){
    const int row=i>>5, j0=(i&31)*4;
    f32x4 yv = *(const f32x4*)&XGE[(r0+row)*192 + j0];
    float tmp[4] = {yv[0],yv[1],yv[2],yv[3]};
    uint2 whi, wlo;
    pack_hilo(tmp, &whi, &wlo);
    const int off = (j0*2) ^ ((row&7)<<4);
    *(uint2*)((char*)yh + row*256 + off) = whi;
    *(uint2*)((char*)yl + row*256 + off) = wlo;
  }
  __syncthreads();

  // B-fragments for this lane's row (walk-row wl of wave wv)
  const int swz = (wl&7)<<4;
  const char* Hb = (const char*)yh + (16*wv+wl)*256;
  const char* Lb = (const char*)yl + (16*wv+wl)*256;
  short8v bh[4], bl[4];
  #pragma unroll
  for (int c=0;c<4;++c){
    bh[c] = *(const short8v*)(Hb + ((c*64 + 16*ag) ^ swz));
    bl[c] = *(const short8v*)(Lb + ((c*64 + 16*ag) ^ swz));
  }

  const short8v* WPv = (const short8v*)WP;
  const int   nd = nd_l[16*wv+wl];
  const float dd = dd_l[16*wv+wl];
  const size_t orow = (r0 + 16*wv + wl)*192;
  const size_t h2b  = (size_t)nd*192;

  #pragma unroll 2
  for (int a=0;a<12;++a){
    f32x4 C = {0.f,0.f,0.f,0.f};
    #pragma unroll
    for (int c=0;c<4;++c){
      short8v whi_ = WPv[(a*8+c*2+0)*64 + lane];
      short8v wlo_ = WPv[(a*8+c*2+1)*64 + lane];
      C = __builtin_amdgcn_mfma_f32_16x16x32_bf16(whi_, bh[c], C, 0,0,0);
      C = __builtin_amdgcn_mfma_f32_16x16x32_bf16(whi_, bl[c], C, 0,0,0);
      C = __builtin_amdgcn_mfma_f32_16x16x32_bf16(wlo_, bh[c], C, 0,0,0);
    }
    const int g0 = 16*a + 4*ag;
    f32x4 h2v = *(const f32x4*)&H2[h2b + g0];
    f32x4 wdv = *(const f32x4*)&sb_wdeg[g0];
    f32x4 bv  = *(const f32x4*)&sb_bias[g0];
    f32x4 o;
    #pragma unroll
    for (int r=0;r<4;++r) o[r] = C[r] + h2v[r] + dd*wdv[r] + bv[r];
    *(f32x4*)&XGE[orow + g0] = o;
  }
}

extern "C" void kernel_launch(void* const* d_in, const int* in_sizes, int n_in,
                              void* d_out, int out_size, void* d_ws, size_t ws_size,
                              hipStream_t stream)
{
  const float* h      = (const float*)d_in[0];
  const float* e      = (const float*)d_in[2];
  const int*   walks  = (const int*)d_in[3];
  const int*   eids   = (const int*)d_in[4];
  const int*   degs   = (const int*)d_in[5];
  const float* wih_wf = (const float*)d_in[6];
  const float* whh_wf = (const float*)d_in[7];
  const float* bih_wf = (const float*)d_in[8];
  const float* bhh_wf = (const float*)d_in[9];
  const float* wih_wb = (const float*)d_in[10];
  const float* whh_wb = (const float*)d_in[11];
  const float* bih_wb = (const float*)d_in[12];
  const float* bhh_wb = (const float*)d_in[13];
  const float* wih_m  = (const float*)d_in[14];
  const float* whh_m  = (const float*)d_in[15];
  const float* bih_m  = (const float*)d_in[16];
  const float* bhh_m  = (const float*)d_in[17];
  const float* w_edge = (const float*)d_in[18];
  float* out = (float*)d_out;
  float* wsf = (float*)d_ws;

  unsigned short* WP = (unsigned short*)(wsf + OFF_WP);
  float* Me   = wsf + OFF_ME;
  float* WmhT = wsf + OFF_WMHT;
  float* wdeg = wsf + OFF_WDEG;
  int*   dmax = (int*)(wsf + OFF_DMAX);
  float* E2   = wsf + OFF_E2;
  float* H2   = wsf + OFF_H2;
  float* XGE  = wsf + OFF_XGE;
  float* HW   = wsf + OFF_HW;
  int*   MND  = (int*)(wsf + OFF_MND);
  float* MDD  = wsf + OFF_MDD;
  float* Tfp  = wsf + OFF_TFP;
  float* Tbp  = wsf + OFF_TBP;
  unsigned short* WB = (unsigned short*)(wsf + OFF_WB);

  hipLaunchKernelGGL(k_init,      dim3(1),    dim3(64), 0, stream, dmax);
  hipLaunchKernelGGL(k_prep_wp,   dim3(192),  dim3(256),0, stream, wih_m, WP);
  hipLaunchKernelGGL(k_prep_wb,   dim3(288),  dim3(256),0, stream, whh_wf,whh_wb,whh_m, WB);
  hipLaunchKernelGGL(k_prep_tblp, dim3(13),   dim3(256),0, stream,
                     wih_wf,bih_wf,bhh_wf, wih_wb,bih_wb,bhh_wb, Tfp,Tbp);
  hipLaunchKernelGGL(k_prep_misc, dim3(61),   dim3(256),0, stream, wih_m,w_edge,Me,WmhT,wdeg);
  hipLaunchKernelGGL(k_degmax,    dim3(1000), dim3(256),0, stream, walks,degs,dmax,HW);
  hipLaunchKernelGGL(k_e2h2,      dim3(NEDGE+NNODE),dim3(192),0, stream,
                     e,Me,bih_m,bhh_m,h,WmhT,E2,H2);
  hipLaunchKernelGGL(k_wgru_m,    dim3(2000), dim3(256),0, stream,
                     walks,degs,dmax, WB, Tfp,Tbp, bhh_wf,bhh_wb, XGE,HW,MND,MDD);
  hipLaunchKernelGGL(k_proj_m,    dim3(4000), dim3(256),0, stream,
                     WP, H2, wdeg, bih_m, bhh_m, MND, MDD, XGE);
  hipLaunchKernelGGL(k_main_m,    dim3(1000), dim3(256),0, stream,
                     eids, WB, bhh_m, XGE, E2, HW, out);
  (void)in_sizes;(void)n_in;(void)out_size;(void)ws_size;
}